// Round 8
// baseline (291.592 us; speedup 1.0000x reference)
//
#include <hip/hip_runtime.h>

// GE2E loss, N=1024 spk, M=32 utt, D=512.
// v8: round-6 base (prep ebf+ck, 256x256 MFMA GEMM, rowred/final) with the
// GEMM restructured for TLP: BK=32, double-buffered LDS = 64 KB total ->
// 2 blocks/CU, 512 wgs all resident in ONE generation (4 waves/SIMD).
// One s_barrier per K-tile (lgkmcnt(0) + vmcnt(0) tile-end protocol);
// stage issued at tile start (full-tile issue->gate distance; co-resident
// block covers the drain). LDS layout: 2 rows per 128B line, phys chunk =
// logical ^ (line&7) (round-5 measured-0-conflict), staged via
// global_load_lds with pre-swizzled source; all ds_read fragment offsets are
// compile-time immediates. XCD mapping keeps ebf panel + ck L2-resident.

#define N_SPK 1024
#define M_UTT 32
#define D_DIM 512
#define NROWS (N_SPK * M_UTT)   // 32768
#define BM 256
#define BN 256
#define NTILES (N_SPK / BN)     // 4
#define MTILES (NROWS / BM)     // 128
#define NWG (MTILES * NTILES)   // 512
#define NKT 16                  // 512 / 32

typedef __attribute__((ext_vector_type(8))) short short8v;  // 8 bf16
typedef __attribute__((ext_vector_type(4))) float f32x4;

__device__ __forceinline__ unsigned short f2bf(float f) {
    union { float f; unsigned int u; } v; v.f = f;
    unsigned int u = v.u;
    u += 0x7fffu + ((u >> 16) & 1u);   // RNE
    return (unsigned short)(u >> 16);
}

__device__ __forceinline__ void gload_lds16(const void* g, void* l) {
    __builtin_amdgcn_global_load_lds(
        (const __attribute__((address_space(1))) unsigned int*)g,
        (__attribute__((address_space(3))) unsigned int*)l, 16, 0, 0);
}

__device__ __forceinline__ float sigmoidf(float x) {
    return 1.f / (1.f + __expf(-x));
}

// ---- k1: emb fp32 -> ebf bf16 and ck bf16 (scaled by sgn(lw)/32) -----------
__global__ void __launch_bounds__(256) prep_kernel(const float* __restrict__ emb,
                                                   const float* __restrict__ lnw,
                                                   unsigned short* __restrict__ ebf,
                                                   unsigned short* __restrict__ ck) {
    __shared__ float part[2][D_DIM];
    const int n = blockIdx.x;
    const int t = threadIdx.x;
    const int d4 = (t & 127) * 4;
    const int mh = t >> 7;
    const float* base = emb + (size_t)n * M_UTT * D_DIM;
    unsigned short* obase = ebf + (size_t)n * M_UTT * D_DIM;

    float4 acc = {0.f, 0.f, 0.f, 0.f};
#pragma unroll
    for (int mm = 0; mm < 16; ++mm) {
        const int m = mh * 16 + mm;
        const float4 v = *reinterpret_cast<const float4*>(base + m * D_DIM + d4);
        acc.x += v.x; acc.y += v.y; acc.z += v.z; acc.w += v.w;
        ushort4 b;
        b.x = f2bf(v.x); b.y = f2bf(v.y); b.z = f2bf(v.z); b.w = f2bf(v.w);
        *reinterpret_cast<ushort4*>(obase + m * D_DIM + d4) = b;
    }
    *reinterpret_cast<float4*>(&part[mh][d4]) = acc;
    __syncthreads();
    if (t < 128) {
        const float sgn = (lnw[0] >= 0.f) ? 1.f : -1.f;
        const float sc = sgn * (1.f / 32.f);
        const int d = t * 4;
        const float4 a = *reinterpret_cast<const float4*>(&part[0][d]);
        const float4 b = *reinterpret_cast<const float4*>(&part[1][d]);
        ushort4 o;
        o.x = f2bf((a.x + b.x) * sc); o.y = f2bf((a.y + b.y) * sc);
        o.z = f2bf((a.z + b.z) * sc); o.w = f2bf((a.w + b.w) * sc);
        *reinterpret_cast<ushort4*>(ck + (size_t)n * D_DIM + d) = o;
    }
}

// ---- k2: BK=32 dbuf GEMM, 2 blocks/CU, 1 barrier per K-tile ----------------
__global__ void __launch_bounds__(512, 4)
gemm_kernel(const unsigned short* __restrict__ ebf,
            const unsigned short* __restrict__ ck,
            float* __restrict__ maxo_part,
            float* __restrict__ own_part) {
    // layout (ushort idx): parity c: A at c*16384, B at c*16384 + 8192.
    // Per half (16 KB = 256 rows x 32 k): line L (128 B) holds rows {2L,2L+1};
    // logical chunk l = (row&1)*4 + k/8, stored at phys = l ^ (L&7).
    __shared__ __align__(16) unsigned short buf[32768];   // 64 KB total

    const int tid  = threadIdx.x;
    const int lane = tid & 63;
    const int wv   = tid >> 6;
    const int lo   = lane & 15;
    const int hi   = lane >> 4;
    const int wm   = wv >> 2;   // 0..1 : 128-row half
    const int wn   = wv & 3;    // 0..3 : 64-col quarter

    // XCD mapping: xcd gets 16 consecutive mt x all 4 nt
    const int raw   = blockIdx.x;
    const int xcd   = raw & 7;
    const int local = raw >> 3;          // 0..63
    const int mt    = xcd * 16 + (local >> 2);
    const int nt    = local & 3;
    const int r0    = mt * BM;
    const int n0    = nt * BN;

    // ---- staging map: 1024 chunks per half, 2 per thread ----
    const unsigned short* pA[2];
    const unsigned short* pB[2];
    int dst[2];
#pragma unroll
    for (int j = 0; j < 2; ++j) {
        const int s   = j * 512 + tid;
        const int L   = s >> 3;
        const int l   = (s & 7) ^ (L & 7);
        const int row = 2 * L + (l >> 2);
        const int kch = l & 3;
        pA[j] = ebf + (size_t)(r0 + row) * D_DIM + kch * 8;
        pB[j] = ck  + (size_t)(n0 + row) * D_DIM + kch * 8;
        dst[j] = s * 8;
    }

    auto stage = [&](int u) {
        const int p = (u & 1) * 16384;
#pragma unroll
        for (int j = 0; j < 2; ++j) {
            gload_lds16(pA[j] + u * 32, &buf[p + dst[j]]);
            gload_lds16(pB[j] + u * 32, &buf[p + 8192 + dst[j]]);
        }
    };

    // prologue
    stage(0);
    asm volatile("s_waitcnt vmcnt(0)" ::: "memory");
    __builtin_amdgcn_s_barrier();
    __builtin_amdgcn_sched_barrier(0);

    // ---- read bases (bytes); phys slot is lane-constant ----
    const int physr = ((((lo & 1) << 2) + hi) ^ ((lo >> 1) & 7)) * 16;
    const int aoffb = (wm * 64 + (lo >> 1)) * 128 + physr;           // A half
    const int boffb = 16384 + (wn * 32 + (lo >> 1)) * 128 + physr;   // B half
    const char* bufc = (const char*)buf;

    f32x4 acc[8][4];
#pragma unroll
    for (int am = 0; am < 8; ++am)
#pragma unroll
        for (int an = 0; an < 4; ++an) acc[am][an] = (f32x4){0.f, 0.f, 0.f, 0.f};

    short8v a[4], b[4];

#pragma unroll
    for (int t = 0; t < NKT; ++t) {
        const int cb = (t & 1) * 32768;   // byte base of this parity

        if (t < NKT - 1) stage(t + 1);

#pragma unroll
        for (int nf = 0; nf < 4; ++nf)
            b[nf] = *reinterpret_cast<const short8v*>(bufc + cb + boffb + nf * 1024);
#pragma unroll
        for (int mf = 0; mf < 4; ++mf)
            a[mf] = *reinterpret_cast<const short8v*>(bufc + cb + aoffb + mf * 1024);

        __builtin_amdgcn_s_setprio(1);
#pragma unroll
        for (int mf = 0; mf < 4; ++mf)
#pragma unroll
            for (int nf = 0; nf < 4; ++nf)
                acc[mf][nf] = __builtin_amdgcn_mfma_f32_16x16x32_bf16(
                    a[mf], b[nf], acc[mf][nf], 0, 0, 0);
        __builtin_amdgcn_s_setprio(0);

#pragma unroll
        for (int mf = 0; mf < 4; ++mf)
            a[mf] = *reinterpret_cast<const short8v*>(bufc + cb + aoffb + 4096 + mf * 1024);

        __builtin_amdgcn_s_setprio(1);
#pragma unroll
        for (int mf = 0; mf < 4; ++mf)
#pragma unroll
            for (int nf = 0; nf < 4; ++nf)
                acc[4 + mf][nf] = __builtin_amdgcn_mfma_f32_16x16x32_bf16(
                    a[mf], b[nf], acc[4 + mf][nf], 0, 0, 0);
        __builtin_amdgcn_s_setprio(0);

        // tile-end protocol: my ds_reads drained; next tile staged; rendezvous
        asm volatile("s_waitcnt lgkmcnt(0)" ::: "memory");
        if (t < NKT - 1) asm volatile("s_waitcnt vmcnt(0)" ::: "memory");
        __builtin_amdgcn_s_barrier();
        __builtin_amdgcn_sched_barrier(0);
    }

    // ---- fold acc -> per-row max (diag excluded) + own; red aliased on buf --
    float* red = (float*)buf;   // 2048 floats used (8 KB)
    const float NEG = -1e30f;

#pragma unroll
    for (int am = 0; am < 8; ++am) {
#pragma unroll
        for (int reg = 0; reg < 4; ++reg) {
            const int rl   = wm * 128 + am * 16 + hi * 4 + reg;
            const int rowg = r0 + rl;
            const int spk  = rowg >> 5;
            float m = NEG, o = NEG;
#pragma unroll
            for (int an = 0; an < 4; ++an) {
                const int col = n0 + wn * 64 + an * 16 + lo;
                const float v = acc[am][an][reg];
                const bool dg = (col == spk);
                o = dg ? v : o;
                m = fmaxf(m, dg ? NEG : v);
            }
#pragma unroll
            for (int mask = 1; mask < 16; mask <<= 1) {
                m = fmaxf(m, __shfl_xor(m, mask));
                o = fmaxf(o, __shfl_xor(o, mask));
            }
            if (lo == 0) {
                red[wn * 256 + rl]        = m;
                red[1024 + wn * 256 + rl] = o;
            }
        }
    }
    __syncthreads();

    if (tid < 256) {
        const float mo = fmaxf(fmaxf(red[tid], red[256 + tid]),
                               fmaxf(red[512 + tid], red[768 + tid]));
        maxo_part[(size_t)nt * NROWS + r0 + tid] = mo;
        if (nt == (mt >> 5)) {
            const float op = fmaxf(fmaxf(red[1024 + tid], red[1280 + tid]),
                                   fmaxf(red[1536 + tid], red[1792 + tid]));
            own_part[r0 + tid] = op;
        }
    }
}

// ---- k3: per-row finish: combine 4 tile-maxes, sigmoid, loss/corr ---------
__global__ void __launch_bounds__(256) rowred_kernel(const float* __restrict__ maxo_part,
                                                     const float* __restrict__ own_part,
                                                     const float* __restrict__ lnw,
                                                     const float* __restrict__ lnb,
                                                     float* __restrict__ partsum) {
    const int r = blockIdx.x * 256 + threadIdx.x;
    const float lw = lnw[0], lb = lnb[0];
    const float sgn = (lw >= 0.f) ? 1.f : -1.f;
    const float alw = fabsf(lw);

    float mo = maxo_part[r];
#pragma unroll
    for (int nt2 = 1; nt2 < NTILES; ++nt2)
        mo = fmaxf(mo, maxo_part[(size_t)nt2 * NROWS + r]);
    const float ownp  = own_part[r];          // sgn-scaled raw dot e.ck_own
    const float s_own = sgn * ownp;
    const float ex    = (32.f * s_own - 1.f) * (1.f / 31.f);
    const float own_s = sigmoidf(lw * ex + lb);
    const float mo_s  = sigmoidf(alw * mo + lb);
    float loss = 1.f - own_s + mo_s;
    float corr = (sgn * ex >= mo) ? 1.f : 0.f;

#pragma unroll
    for (int mask = 1; mask < 64; mask <<= 1) {
        loss += __shfl_xor(loss, mask);
        corr += __shfl_xor(corr, mask);
    }
    __shared__ float sl[4], sc[4];
    const int wv = threadIdx.x >> 6;
    if ((threadIdx.x & 63) == 0) { sl[wv] = loss; sc[wv] = corr; }
    __syncthreads();
    if (threadIdx.x == 0) {
        partsum[blockIdx.x]       = sl[0] + sl[1] + sl[2] + sl[3];
        partsum[128 + blockIdx.x] = sc[0] + sc[1] + sc[2] + sc[3];
    }
}

// ---- k4: final scalar reduce ----------------------------------------------
__global__ void __launch_bounds__(128) final_kernel(const float* __restrict__ partsum,
                                                    float* __restrict__ out) {
    const int t = threadIdx.x;
    float l = partsum[t];
    float c = partsum[128 + t];
#pragma unroll
    for (int mask = 1; mask < 64; mask <<= 1) {
        l += __shfl_xor(l, mask);
        c += __shfl_xor(c, mask);
    }
    __shared__ float sl[2], sc[2];
    if ((t & 63) == 0) { sl[t >> 6] = l; sc[t >> 6] = c; }
    __syncthreads();
    if (t == 0) {
        out[0] = (sl[0] + sl[1]) * (1.f / (float)NROWS);
        out[1] = (sc[0] + sc[1]) * (1.f / (float)NROWS);
    }
}

extern "C" void kernel_launch(void* const* d_in, const int* in_sizes, int n_in,
                              void* d_out, int out_size, void* d_ws, size_t ws_size,
                              hipStream_t stream) {
    (void)in_sizes; (void)n_in; (void)out_size; (void)ws_size;
    const float* emb = (const float*)d_in[0];
    const float* lnw = (const float*)d_in[3];
    const float* lnb = (const float*)d_in[4];
    float* out = (float*)d_out;

    char* ws = (char*)d_ws;
    unsigned short* ebf = (unsigned short*)ws;                                   // 32 MB
    unsigned short* ck  = (unsigned short*)(ws + (size_t)NROWS * D_DIM * 2);     // 1 MB
    float* maxo_part = (float*)(ws + (size_t)NROWS * D_DIM * 2
                                   + (size_t)N_SPK * D_DIM * 2);                 // 512 KB
    float* own_part  = (float*)((char*)maxo_part + (size_t)NTILES * NROWS * 4);  // 128 KB
    float* partsum   = (float*)((char*)own_part + (size_t)NROWS * 4);            // 1 KB

    prep_kernel<<<N_SPK, 256, 0, stream>>>(emb, lnw, ebf, ck);
    gemm_kernel<<<NWG, 512, 0, stream>>>(ebf, ck, maxo_part, own_part);
    rowred_kernel<<<NROWS / 256, 256, 0, stream>>>(maxo_part, own_part, lnw, lnb, partsum);
    final_kernel<<<1, 128, 0, stream>>>(partsum, out);
}

// Round 9
// 82.746 us; speedup vs baseline: 3.5239x; 3.5239x over previous
//
#include <hip/hip_runtime.h>

// GE2E loss, N=1024 spk, M=32 utt, D=512.
// v9: round-6 8-phase template, ONE generation. Grid = 256 blocks (1 per CU);
// each block = 256 rows x 512 cols, run as two sequential 256-col subtiles
// over a single continuous 16-K-tile pipeline (B row-base switches at tile 8,
// A rewinds to k=0 and re-hits L2). Fill/drain/epilogue amortized 2x, no
// inter-generation gap. Fold to registers at tau=7/15; one shfl+LDS reduce at
// the end. All round-6 schedule details (vmcnt(4) counted gate, measured-0-
// conflict XOR layout, global_load_lds staging, setprio) unchanged.

#define N_SPK 1024
#define M_UTT 32
#define D_DIM 512
#define NROWS (N_SPK * M_UTT)   // 32768
#define BM 256
#define NPARTS 2                // col halves (512 each)
#define GRID_G 256
#define NKT 16                  // 2 subtiles x 8 K-tiles (BK=64)

typedef __attribute__((ext_vector_type(8))) short short8v;  // 8 bf16
typedef __attribute__((ext_vector_type(4))) float f32x4;

__device__ __forceinline__ unsigned short f2bf(float f) {
    union { float f; unsigned int u; } v; v.f = f;
    unsigned int u = v.u;
    u += 0x7fffu + ((u >> 16) & 1u);   // RNE
    return (unsigned short)(u >> 16);
}

__device__ __forceinline__ void gload_lds16(const void* g, void* l) {
    __builtin_amdgcn_global_load_lds(
        (const __attribute__((address_space(1))) unsigned int*)g,
        (__attribute__((address_space(3))) unsigned int*)l, 16, 0, 0);
}

__device__ __forceinline__ float sigmoidf(float x) {
    return 1.f / (1.f + __expf(-x));
}

template <int MH, int NH>
__device__ __forceinline__ void qmm(f32x4 (&acc)[8][4],
                                    const short8v (&a)[4][2],
                                    const short8v (&b)[2][2]) {
#pragma unroll
    for (int mf = 0; mf < 4; ++mf)
#pragma unroll
        for (int nf = 0; nf < 2; ++nf) {
            acc[MH * 4 + mf][NH * 2 + nf] = __builtin_amdgcn_mfma_f32_16x16x32_bf16(
                a[mf][0], b[nf][0], acc[MH * 4 + mf][NH * 2 + nf], 0, 0, 0);
            acc[MH * 4 + mf][NH * 2 + nf] = __builtin_amdgcn_mfma_f32_16x16x32_bf16(
                a[mf][1], b[nf][1], acc[MH * 4 + mf][NH * 2 + nf], 0, 0, 0);
        }
}

// ---- k1: emb fp32 -> ebf bf16 and ck bf16 (scaled by sgn(lw)/32) -----------
__global__ void __launch_bounds__(256) prep_kernel(const float* __restrict__ emb,
                                                   const float* __restrict__ lnw,
                                                   unsigned short* __restrict__ ebf,
                                                   unsigned short* __restrict__ ck) {
    __shared__ float part[2][D_DIM];
    const int n = blockIdx.x;
    const int t = threadIdx.x;
    const int d4 = (t & 127) * 4;
    const int mh = t >> 7;
    const float* base = emb + (size_t)n * M_UTT * D_DIM;
    unsigned short* obase = ebf + (size_t)n * M_UTT * D_DIM;

    float4 acc = {0.f, 0.f, 0.f, 0.f};
#pragma unroll
    for (int mm = 0; mm < 16; ++mm) {
        const int m = mh * 16 + mm;
        const float4 v = *reinterpret_cast<const float4*>(base + m * D_DIM + d4);
        acc.x += v.x; acc.y += v.y; acc.z += v.z; acc.w += v.w;
        ushort4 b;
        b.x = f2bf(v.x); b.y = f2bf(v.y); b.z = f2bf(v.z); b.w = f2bf(v.w);
        *reinterpret_cast<ushort4*>(obase + m * D_DIM + d4) = b;
    }
    *reinterpret_cast<float4*>(&part[mh][d4]) = acc;
    __syncthreads();
    if (t < 128) {
        const float sgn = (lnw[0] >= 0.f) ? 1.f : -1.f;
        const float sc = sgn * (1.f / 32.f);
        const int d = t * 4;
        const float4 a = *reinterpret_cast<const float4*>(&part[0][d]);
        const float4 b = *reinterpret_cast<const float4*>(&part[1][d]);
        ushort4 o;
        o.x = f2bf((a.x + b.x) * sc); o.y = f2bf((a.y + b.y) * sc);
        o.z = f2bf((a.z + b.z) * sc); o.w = f2bf((a.w + b.w) * sc);
        *reinterpret_cast<ushort4*>(ck + (size_t)n * D_DIM + d) = o;
    }
}

// ---- k2: one-generation 8-phase GEMM, 256 rows x 512 cols per block --------
__global__ void __launch_bounds__(512, 2)
gemm_kernel(const unsigned short* __restrict__ ebf,
            const unsigned short* __restrict__ ck,
            float* __restrict__ maxo_part,
            float* __restrict__ own_part) {
    // Per buffer (64 KB): A 256x64 bf16 at ushort [0,16384), B at [16384,32768)
    // row r, logical 16B-chunk l stored at phys slot l^(r&7).
    __shared__ __align__(16) unsigned short ring[2][32768];   // 128 KB

    const int tid  = threadIdx.x;
    const int lane = tid & 63;
    const int wv   = tid >> 6;
    const int lo   = lane & 15;
    const int hi   = lane >> 4;
    const int wm   = wv >> 2;   // 0..1 : 128-row half
    const int wn   = wv & 3;    // 0..3 : 64-col quarter

    // XCD mapping: xcd gets 16 consecutive mt x both col halves
    const int raw   = blockIdx.x;
    const int xcd   = raw & 7;
    const int local = raw >> 3;          // 0..31
    const int mt    = xcd * 16 + (local & 15);
    const int ch    = local >> 4;        // col half 0/1
    const int r0    = mt * BM;
    const int c0    = ch * 512;

    // ---- staging map: half-tile = 128 rows x 64 k = 1024 16B-chunks ----
    const unsigned short* pA[2];
    const unsigned short* pB[2];
    int doff[2];
#pragma unroll
    for (int j = 0; j < 2; ++j) {
        const int s   = j * 512 + tid;
        const int row = s >> 3;
        const int l   = (s & 7) ^ (row & 7);
        pA[j] = ebf + (size_t)(r0 + row) * D_DIM + l * 8;
        pB[j] = ck  + (size_t)(c0 + row) * D_DIM + l * 8;
        doff[j] = s * 8;   // ushort units within a 16 KB half
    }

    // tile tau in [0,16): subtile ntl = tau>>3, k-offset (tau&7)*64
    auto stage_h = [&](int tile, int h) {
        unsigned short* dst = &ring[tile & 1][0];
        const int offA = (tile & 7) * 64 + h * (128 * D_DIM);
        const int offB = offA + ((tile >> 3) << 17);   // +256 rows per subtile
#pragma unroll
        for (int j = 0; j < 2; ++j) {
            gload_lds16(pA[j] + offA, dst + h * 8192 + doff[j]);
            gload_lds16(pB[j] + offB, dst + 16384 + h * 8192 + doff[j]);
        }
    };

    // prologue: tile0 fully + tile1 half0 in flight; gate tile0
    stage_h(0, 0);
    stage_h(0, 1);
    stage_h(1, 0);
    asm volatile("s_waitcnt vmcnt(4)" ::: "memory");
    __builtin_amdgcn_s_barrier();
    __builtin_amdgcn_sched_barrier(0);

    const int ph0   = (hi ^ (lo & 7)) * 16;        // kk=0 chunk byte offset
    const int ph1   = ((4 + hi) ^ (lo & 7)) * 16;  // kk=1
    const int arow0 = (wm * 128 + lo) * 128;       // A byte base (mf=0, mh=0)
    const int bcol0 = 32768 + (wn * 64 + lo) * 128;// B byte base (nf=0, nh=0)

    f32x4 acc[8][4];
    float mx[8][4], ow[8][4];
    const float NEG = -1e30f;
#pragma unroll
    for (int am = 0; am < 8; ++am)
#pragma unroll
        for (int an = 0; an < 4; ++an) acc[am][an] = (f32x4){0.f, 0.f, 0.f, 0.f};
#pragma unroll
    for (int am = 0; am < 8; ++am)
#pragma unroll
        for (int reg = 0; reg < 4; ++reg) { mx[am][reg] = NEG; ow[am][reg] = NEG; }

    short8v a[4][2], b0c[2][2], b1c[2][2];

#pragma unroll
    for (int t = 0; t < NKT; ++t) {
        const char* bufp = (const char*)&ring[t & 1][0];

        // ---- phase 0: read a(mh0)+b(nh0); stage (t+1,h1); Q(0,0) ----
#pragma unroll
        for (int mf = 0; mf < 4; ++mf) {
            a[mf][0] = *reinterpret_cast<const short8v*>(bufp + arow0 + mf * 2048 + ph0);
            a[mf][1] = *reinterpret_cast<const short8v*>(bufp + arow0 + mf * 2048 + ph1);
        }
#pragma unroll
        for (int nf = 0; nf < 2; ++nf) {
            b0c[nf][0] = *reinterpret_cast<const short8v*>(bufp + bcol0 + nf * 2048 + ph0);
            b0c[nf][1] = *reinterpret_cast<const short8v*>(bufp + bcol0 + nf * 2048 + ph1);
        }
        if (t < NKT - 1) stage_h(t + 1, 1);
        __builtin_amdgcn_s_barrier();
        __builtin_amdgcn_s_setprio(1);
        qmm<0, 0>(acc, a, b0c);
        __builtin_amdgcn_s_setprio(0);
        __builtin_amdgcn_s_barrier();

        // ---- phase 1: read b(nh1); Q(0,1) ----
#pragma unroll
        for (int nf = 0; nf < 2; ++nf) {
            b1c[nf][0] = *reinterpret_cast<const short8v*>(bufp + bcol0 + 4096 + nf * 2048 + ph0);
            b1c[nf][1] = *reinterpret_cast<const short8v*>(bufp + bcol0 + 4096 + nf * 2048 + ph1);
        }
        __builtin_amdgcn_s_barrier();
        __builtin_amdgcn_s_setprio(1);
        qmm<0, 1>(acc, a, b1c);
        __builtin_amdgcn_s_setprio(0);
        __builtin_amdgcn_s_barrier();

        // ---- phase 2: read a(mh1); Q(1,1) ----
#pragma unroll
        for (int mf = 0; mf < 4; ++mf) {
            a[mf][0] = *reinterpret_cast<const short8v*>(bufp + arow0 + 8192 + mf * 2048 + ph0);
            a[mf][1] = *reinterpret_cast<const short8v*>(bufp + arow0 + 8192 + mf * 2048 + ph1);
        }
        __builtin_amdgcn_s_barrier();
        __builtin_amdgcn_s_setprio(1);
        qmm<1, 1>(acc, a, b1c);
        __builtin_amdgcn_s_setprio(0);
        __builtin_amdgcn_s_barrier();

        // ---- phase 3: stage (t+2,h0); Q(1,0); counted gate ----
        if (t < NKT - 2) stage_h(t + 2, 0);
        __builtin_amdgcn_s_barrier();
        __builtin_amdgcn_s_setprio(1);
        qmm<1, 0>(acc, a, b0c);
        __builtin_amdgcn_s_setprio(0);
        if (t < NKT - 2)       asm volatile("s_waitcnt vmcnt(4)" ::: "memory");
        else if (t == NKT - 2) asm volatile("s_waitcnt vmcnt(0)" ::: "memory");
        __builtin_amdgcn_s_barrier();
        __builtin_amdgcn_sched_barrier(0);

        // ---- subtile boundary: register-only fold, reset acc ----
        if (t == 7 || t == 15) {
            const int ntl = t >> 3;
#pragma unroll
            for (int am = 0; am < 8; ++am)
#pragma unroll
                for (int reg = 0; reg < 4; ++reg) {
                    const int rowg = r0 + wm * 128 + am * 16 + hi * 4 + reg;
                    const int spk  = rowg >> 5;
#pragma unroll
                    for (int an = 0; an < 4; ++an) {
                        const int col = c0 + ntl * 256 + wn * 64 + an * 16 + lo;
                        const float v = acc[am][an][reg];
                        const bool dg = (col == spk);
                        ow[am][reg] = dg ? v : ow[am][reg];
                        mx[am][reg] = fmaxf(mx[am][reg], dg ? NEG : v);
                    }
                }
            if (t == 7) {
#pragma unroll
                for (int am = 0; am < 8; ++am)
#pragma unroll
                    for (int an = 0; an < 4; ++an)
                        acc[am][an] = (f32x4){0.f, 0.f, 0.f, 0.f};
            }
        }
    }

    // ---- epilogue: shfl-reduce over 16 lanes, LDS combine over wn ----
    __syncthreads();
    float* red = (float*)&ring[0][0];   // ring dead; 2048 floats used

#pragma unroll
    for (int am = 0; am < 8; ++am) {
#pragma unroll
        for (int reg = 0; reg < 4; ++reg) {
            float m = mx[am][reg], o = ow[am][reg];
#pragma unroll
            for (int mask = 1; mask < 16; mask <<= 1) {
                m = fmaxf(m, __shfl_xor(m, mask));
                o = fmaxf(o, __shfl_xor(o, mask));
            }
            if (lo == 0) {
                const int rl = wm * 128 + am * 16 + hi * 4 + reg;
                red[wn * 256 + rl]        = m;
                red[1024 + wn * 256 + rl] = o;
            }
        }
    }
    __syncthreads();

    if (tid < 256) {
        const float mo = fmaxf(fmaxf(red[tid], red[256 + tid]),
                               fmaxf(red[512 + tid], red[768 + tid]));
        maxo_part[(size_t)ch * NROWS + r0 + tid] = mo;
        if (ch == (mt >> 6)) {
            const float op = fmaxf(fmaxf(red[1024 + tid], red[1280 + tid]),
                                   fmaxf(red[1536 + tid], red[1792 + tid]));
            own_part[r0 + tid] = op;
        }
    }
}

// ---- k3: per-row finish: combine 2 half-maxes, sigmoid, loss/corr ----------
__global__ void __launch_bounds__(256) rowred_kernel(const float* __restrict__ maxo_part,
                                                     const float* __restrict__ own_part,
                                                     const float* __restrict__ lnw,
                                                     const float* __restrict__ lnb,
                                                     float* __restrict__ partsum) {
    const int r = blockIdx.x * 256 + threadIdx.x;
    const float lw = lnw[0], lb = lnb[0];
    const float sgn = (lw >= 0.f) ? 1.f : -1.f;
    const float alw = fabsf(lw);

    const float mo = fmaxf(maxo_part[r], maxo_part[(size_t)NROWS + r]);
    const float ownp  = own_part[r];          // sgn-scaled raw dot e.ck_own
    const float s_own = sgn * ownp;
    const float ex    = (32.f * s_own - 1.f) * (1.f / 31.f);
    const float own_s = sigmoidf(lw * ex + lb);
    const float mo_s  = sigmoidf(alw * mo + lb);
    float loss = 1.f - own_s + mo_s;
    float corr = (sgn * ex >= mo) ? 1.f : 0.f;

#pragma unroll
    for (int mask = 1; mask < 64; mask <<= 1) {
        loss += __shfl_xor(loss, mask);
        corr += __shfl_xor(corr, mask);
    }
    __shared__ float sl[4], sc[4];
    const int wv = threadIdx.x >> 6;
    if ((threadIdx.x & 63) == 0) { sl[wv] = loss; sc[wv] = corr; }
    __syncthreads();
    if (threadIdx.x == 0) {
        partsum[blockIdx.x]       = sl[0] + sl[1] + sl[2] + sl[3];
        partsum[128 + blockIdx.x] = sc[0] + sc[1] + sc[2] + sc[3];
    }
}

// ---- k4: final scalar reduce ----------------------------------------------
__global__ void __launch_bounds__(128) final_kernel(const float* __restrict__ partsum,
                                                    float* __restrict__ out) {
    const int t = threadIdx.x;
    float l = partsum[t];
    float c = partsum[128 + t];
#pragma unroll
    for (int mask = 1; mask < 64; mask <<= 1) {
        l += __shfl_xor(l, mask);
        c += __shfl_xor(c, mask);
    }
    __shared__ float sl[2], sc[2];
    if ((t & 63) == 0) { sl[t >> 6] = l; sc[t >> 6] = c; }
    __syncthreads();
    if (t == 0) {
        out[0] = (sl[0] + sl[1]) * (1.f / (float)NROWS);
        out[1] = (sc[0] + sc[1]) * (1.f / (float)NROWS);
    }
}

extern "C" void kernel_launch(void* const* d_in, const int* in_sizes, int n_in,
                              void* d_out, int out_size, void* d_ws, size_t ws_size,
                              hipStream_t stream) {
    (void)in_sizes; (void)n_in; (void)out_size; (void)ws_size;
    const float* emb = (const float*)d_in[0];
    const float* lnw = (const float*)d_in[3];
    const float* lnb = (const float*)d_in[4];
    float* out = (float*)d_out;

    char* ws = (char*)d_ws;
    unsigned short* ebf = (unsigned short*)ws;                                   // 32 MB
    unsigned short* ck  = (unsigned short*)(ws + (size_t)NROWS * D_DIM * 2);     // 1 MB
    float* maxo_part = (float*)(ws + (size_t)NROWS * D_DIM * 2
                                   + (size_t)N_SPK * D_DIM * 2);                 // 256 KB
    float* own_part  = (float*)((char*)maxo_part + (size_t)NPARTS * NROWS * 4);  // 128 KB
    float* partsum   = (float*)((char*)own_part + (size_t)NROWS * 4);            // 1 KB

    prep_kernel<<<N_SPK, 256, 0, stream>>>(emb, lnw, ebf, ck);
    gemm_kernel<<<GRID_G, 512, 0, stream>>>(ebf, ck, maxo_part, own_part);
    rowred_kernel<<<NROWS / 256, 256, 0, stream>>>(maxo_part, own_part, lnw, lnb, partsum);
    final_kernel<<<1, 128, 0, stream>>>(partsum, out);
}

// Round 10
// 70.772 us; speedup vs baseline: 4.1202x; 1.1692x over previous
//
#include <hip/hip_runtime.h>

// GE2E loss, N=1024 spk, M=32 utt, D=512.
// v10: round-6 8-phase template, ONE generation, no extra register state.
// Grid = 256 blocks (1/CU); block = 512 rows (row-pair P) x 256 cols (nt).
// 16 K-tiles: tiles 0-7 = rows[0:256) k 0..512; tiles 8-15 = rows[256:512)
// (A row-half switch at tau=8; B rewinds k, 256 KB panel stays L2-resident).
// Subtile fold at tau=7/15 via shfl + separate 16 KB red LDS (transient regs
// only -> no spill; ring 128 KB + red 16 KB = 144 KB). Schedule = round 6
// verbatim: 4 phases/K-tile, counted vmcnt(4) gate, measured-0-conflict
// chunk^(row&7) XOR layout, global_load_lds staging, setprio.

#define N_SPK 1024
#define M_UTT 32
#define D_DIM 512
#define NROWS (N_SPK * M_UTT)   // 32768
#define NTILES 4                // col tiles of 256
#define GRID_G 256
#define NKT 16                  // 2 row-halves x 8 K-tiles (BK=64)

typedef __attribute__((ext_vector_type(8))) short short8v;  // 8 bf16
typedef __attribute__((ext_vector_type(4))) float f32x4;

__device__ __forceinline__ unsigned short f2bf(float f) {
    union { float f; unsigned int u; } v; v.f = f;
    unsigned int u = v.u;
    u += 0x7fffu + ((u >> 16) & 1u);   // RNE
    return (unsigned short)(u >> 16);
}

__device__ __forceinline__ void gload_lds16(const void* g, void* l) {
    __builtin_amdgcn_global_load_lds(
        (const __attribute__((address_space(1))) unsigned int*)g,
        (__attribute__((address_space(3))) unsigned int*)l, 16, 0, 0);
}

__device__ __forceinline__ float sigmoidf(float x) {
    return 1.f / (1.f + __expf(-x));
}

template <int MH, int NH>
__device__ __forceinline__ void qmm(f32x4 (&acc)[8][4],
                                    const short8v (&a)[4][2],
                                    const short8v (&b)[2][2]) {
#pragma unroll
    for (int mf = 0; mf < 4; ++mf)
#pragma unroll
        for (int nf = 0; nf < 2; ++nf) {
            acc[MH * 4 + mf][NH * 2 + nf] = __builtin_amdgcn_mfma_f32_16x16x32_bf16(
                a[mf][0], b[nf][0], acc[MH * 4 + mf][NH * 2 + nf], 0, 0, 0);
            acc[MH * 4 + mf][NH * 2 + nf] = __builtin_amdgcn_mfma_f32_16x16x32_bf16(
                a[mf][1], b[nf][1], acc[MH * 4 + mf][NH * 2 + nf], 0, 0, 0);
        }
}

// ---- k1: emb fp32 -> ebf bf16 and ck bf16 (scaled by sgn(lw)/32) -----------
__global__ void __launch_bounds__(256) prep_kernel(const float* __restrict__ emb,
                                                   const float* __restrict__ lnw,
                                                   unsigned short* __restrict__ ebf,
                                                   unsigned short* __restrict__ ck) {
    __shared__ float part[2][D_DIM];
    const int n = blockIdx.x;
    const int t = threadIdx.x;
    const int d4 = (t & 127) * 4;
    const int mh = t >> 7;
    const float* base = emb + (size_t)n * M_UTT * D_DIM;
    unsigned short* obase = ebf + (size_t)n * M_UTT * D_DIM;

    float4 acc = {0.f, 0.f, 0.f, 0.f};
#pragma unroll
    for (int mm = 0; mm < 16; ++mm) {
        const int m = mh * 16 + mm;
        const float4 v = *reinterpret_cast<const float4*>(base + m * D_DIM + d4);
        acc.x += v.x; acc.y += v.y; acc.z += v.z; acc.w += v.w;
        ushort4 b;
        b.x = f2bf(v.x); b.y = f2bf(v.y); b.z = f2bf(v.z); b.w = f2bf(v.w);
        *reinterpret_cast<ushort4*>(obase + m * D_DIM + d4) = b;
    }
    *reinterpret_cast<float4*>(&part[mh][d4]) = acc;
    __syncthreads();
    if (t < 128) {
        const float sgn = (lnw[0] >= 0.f) ? 1.f : -1.f;
        const float sc = sgn * (1.f / 32.f);
        const int d = t * 4;
        const float4 a = *reinterpret_cast<const float4*>(&part[0][d]);
        const float4 b = *reinterpret_cast<const float4*>(&part[1][d]);
        ushort4 o;
        o.x = f2bf((a.x + b.x) * sc); o.y = f2bf((a.y + b.y) * sc);
        o.z = f2bf((a.z + b.z) * sc); o.w = f2bf((a.w + b.w) * sc);
        *reinterpret_cast<ushort4*>(ck + (size_t)n * D_DIM + d) = o;
    }
}

// ---- k2: one-generation 8-phase GEMM, 512 rows x 256 cols per block --------
__global__ void __launch_bounds__(512, 2)
gemm_kernel(const unsigned short* __restrict__ ebf,
            const unsigned short* __restrict__ ck,
            float* __restrict__ maxo_part,
            float* __restrict__ own_part) {
    // Per buffer (64 KB): A 256x64 bf16 at ushort [0,16384), B at [16384,32768)
    // row r, logical 16B-chunk l stored at phys slot l^(r&7).
    __shared__ __align__(16) unsigned short ring[2][32768];   // 128 KB
    __shared__ float red[2][2][4][256];                       // 16 KB

    const int tid  = threadIdx.x;
    const int lane = tid & 63;
    const int wv   = tid >> 6;
    const int lo   = lane & 15;
    const int hi   = lane >> 4;
    const int wm   = wv >> 2;   // 0..1 : 128-row half
    const int wn   = wv & 3;    // 0..3 : 64-col quarter

    // XCD mapping: xcd gets 8 consecutive row-pairs x all 4 nt
    const int raw   = blockIdx.x;
    const int xcd   = raw & 7;
    const int local = raw >> 3;          // 0..31
    const int P     = xcd * 8 + (local >> 2);   // 0..63
    const int nt    = local & 3;
    const int r0    = P * 512;
    const int n0    = nt * 256;

    // ---- staging map: half-tile = 128 rows x 64 k = 1024 16B-chunks ----
    const unsigned short* pA[2];
    const unsigned short* pB[2];
    int doff[2];
#pragma unroll
    for (int j = 0; j < 2; ++j) {
        const int s   = j * 512 + tid;
        const int row = s >> 3;
        const int l   = (s & 7) ^ (row & 7);
        pA[j] = ebf + (size_t)(r0 + row) * D_DIM + l * 8;
        pB[j] = ck  + (size_t)(n0 + row) * D_DIM + l * 8;
        doff[j] = s * 8;   // ushort units within a 16 KB half
    }

    // tile tau in [0,16): row-half = tau>>3, k-offset (tau&7)*64
    auto stage_h = [&](int tile, int h) {
        unsigned short* dst = &ring[tile & 1][0];
        const int offA = (tile & 7) * 64 + ((tile >> 3) << 17) + (h << 16);
        const int offB = (tile & 7) * 64 + (h << 16);
#pragma unroll
        for (int j = 0; j < 2; ++j) {
            gload_lds16(pA[j] + offA, dst + h * 8192 + doff[j]);
            gload_lds16(pB[j] + offB, dst + 16384 + h * 8192 + doff[j]);
        }
    };

    // prologue: tile0 fully + tile1 half0 in flight; gate tile0
    stage_h(0, 0);
    stage_h(0, 1);
    stage_h(1, 0);
    asm volatile("s_waitcnt vmcnt(4)" ::: "memory");
    __builtin_amdgcn_s_barrier();
    __builtin_amdgcn_sched_barrier(0);

    const int ph0   = (hi ^ (lo & 7)) * 16;        // kk=0 chunk byte offset
    const int ph1   = ((4 + hi) ^ (lo & 7)) * 16;  // kk=1
    const int arow0 = (wm * 128 + lo) * 128;       // A byte base (mf=0, mh=0)
    const int bcol0 = 32768 + (wn * 64 + lo) * 128;// B byte base (nf=0, nh=0)

    f32x4 acc[8][4];
    const float NEG = -1e30f;
#pragma unroll
    for (int am = 0; am < 8; ++am)
#pragma unroll
        for (int an = 0; an < 4; ++an) acc[am][an] = (f32x4){0.f, 0.f, 0.f, 0.f};

    short8v a[4][2], b0c[2][2], b1c[2][2];

    for (int t = 0; t < NKT; ++t) {
        const char* bufp = (const char*)&ring[t & 1][0];

        // ---- phase 0: read a(mh0)+b(nh0); stage (t+1,h1); Q(0,0) ----
#pragma unroll
        for (int mf = 0; mf < 4; ++mf) {
            a[mf][0] = *reinterpret_cast<const short8v*>(bufp + arow0 + mf * 2048 + ph0);
            a[mf][1] = *reinterpret_cast<const short8v*>(bufp + arow0 + mf * 2048 + ph1);
        }
#pragma unroll
        for (int nf = 0; nf < 2; ++nf) {
            b0c[nf][0] = *reinterpret_cast<const short8v*>(bufp + bcol0 + nf * 2048 + ph0);
            b0c[nf][1] = *reinterpret_cast<const short8v*>(bufp + bcol0 + nf * 2048 + ph1);
        }
        if (t < NKT - 1) stage_h(t + 1, 1);
        __builtin_amdgcn_s_barrier();
        __builtin_amdgcn_s_setprio(1);
        qmm<0, 0>(acc, a, b0c);
        __builtin_amdgcn_s_setprio(0);
        __builtin_amdgcn_s_barrier();

        // ---- phase 1: read b(nh1); Q(0,1) ----
#pragma unroll
        for (int nf = 0; nf < 2; ++nf) {
            b1c[nf][0] = *reinterpret_cast<const short8v*>(bufp + bcol0 + 4096 + nf * 2048 + ph0);
            b1c[nf][1] = *reinterpret_cast<const short8v*>(bufp + bcol0 + 4096 + nf * 2048 + ph1);
        }
        __builtin_amdgcn_s_barrier();
        __builtin_amdgcn_s_setprio(1);
        qmm<0, 1>(acc, a, b1c);
        __builtin_amdgcn_s_setprio(0);
        __builtin_amdgcn_s_barrier();

        // ---- phase 2: read a(mh1); Q(1,1) ----
#pragma unroll
        for (int mf = 0; mf < 4; ++mf) {
            a[mf][0] = *reinterpret_cast<const short8v*>(bufp + arow0 + 8192 + mf * 2048 + ph0);
            a[mf][1] = *reinterpret_cast<const short8v*>(bufp + arow0 + 8192 + mf * 2048 + ph1);
        }
        __builtin_amdgcn_s_barrier();
        __builtin_amdgcn_s_setprio(1);
        qmm<1, 1>(acc, a, b1c);
        __builtin_amdgcn_s_setprio(0);
        __builtin_amdgcn_s_barrier();

        // ---- phase 3: stage (t+2,h0); Q(1,0); counted gate ----
        if (t < NKT - 2) stage_h(t + 2, 0);
        __builtin_amdgcn_s_barrier();
        __builtin_amdgcn_s_setprio(1);
        qmm<1, 0>(acc, a, b0c);
        __builtin_amdgcn_s_setprio(0);
        if (t < NKT - 2)       asm volatile("s_waitcnt vmcnt(4)" ::: "memory");
        else if (t == NKT - 2) asm volatile("s_waitcnt vmcnt(0)" ::: "memory");
        __builtin_amdgcn_s_barrier();
        __builtin_amdgcn_sched_barrier(0);

        // ---- row-half boundary: fold acc -> red (transient regs only) ----
        if (t == 7 || t == 15) {
            const int pass = t >> 3;
#pragma unroll
            for (int am = 0; am < 8; ++am) {
#pragma unroll
                for (int reg = 0; reg < 4; ++reg) {
                    const int rl   = wm * 128 + am * 16 + hi * 4 + reg;
                    const int rowg = r0 + pass * 256 + rl;
                    const int spk  = rowg >> 5;
                    float m = NEG, o = NEG;
#pragma unroll
                    for (int an = 0; an < 4; ++an) {
                        const int col = n0 + wn * 64 + an * 16 + lo;
                        const float v = acc[am][an][reg];
                        const bool dg = (col == spk);
                        o = dg ? v : o;
                        m = fmaxf(m, dg ? NEG : v);
                    }
#pragma unroll
                    for (int mask = 1; mask < 16; mask <<= 1) {
                        m = fmaxf(m, __shfl_xor(m, mask));
                        o = fmaxf(o, __shfl_xor(o, mask));
                    }
                    if (lo == 0) {
                        red[pass][0][wn][rl] = m;
                        red[pass][1][wn][rl] = o;
                    }
                }
            }
            if (t == 7) {
#pragma unroll
                for (int am = 0; am < 8; ++am)
#pragma unroll
                    for (int an = 0; an < 4; ++an)
                        acc[am][an] = (f32x4){0.f, 0.f, 0.f, 0.f};
            }
        }
    }

    // ---- final combine + global writes ----
    __syncthreads();
    if (tid < 256) {
#pragma unroll
        for (int pass = 0; pass < 2; ++pass) {
            const int row = r0 + pass * 256 + tid;
            const float mo = fmaxf(fmaxf(red[pass][0][0][tid], red[pass][0][1][tid]),
                                   fmaxf(red[pass][0][2][tid], red[pass][0][3][tid]));
            maxo_part[(size_t)nt * NROWS + row] = mo;
            if (nt == (row >> 13)) {
                const float op = fmaxf(fmaxf(red[pass][1][0][tid], red[pass][1][1][tid]),
                                       fmaxf(red[pass][1][2][tid], red[pass][1][3][tid]));
                own_part[row] = op;
            }
        }
    }
}

// ---- k3: per-row finish: combine 4 tile-maxes, sigmoid, loss/corr ---------
__global__ void __launch_bounds__(256) rowred_kernel(const float* __restrict__ maxo_part,
                                                     const float* __restrict__ own_part,
                                                     const float* __restrict__ lnw,
                                                     const float* __restrict__ lnb,
                                                     float* __restrict__ partsum) {
    const int r = blockIdx.x * 256 + threadIdx.x;
    const float lw = lnw[0], lb = lnb[0];
    const float sgn = (lw >= 0.f) ? 1.f : -1.f;
    const float alw = fabsf(lw);

    float mo = maxo_part[r];
#pragma unroll
    for (int nt2 = 1; nt2 < NTILES; ++nt2)
        mo = fmaxf(mo, maxo_part[(size_t)nt2 * NROWS + r]);
    const float ownp  = own_part[r];          // sgn-scaled raw dot e.ck_own
    const float s_own = sgn * ownp;
    const float ex    = (32.f * s_own - 1.f) * (1.f / 31.f);
    const float own_s = sigmoidf(lw * ex + lb);
    const float mo_s  = sigmoidf(alw * mo + lb);
    float loss = 1.f - own_s + mo_s;
    float corr = (sgn * ex >= mo) ? 1.f : 0.f;

#pragma unroll
    for (int mask = 1; mask < 64; mask <<= 1) {
        loss += __shfl_xor(loss, mask);
        corr += __shfl_xor(corr, mask);
    }
    __shared__ float sl[4], sc[4];
    const int wv = threadIdx.x >> 6;
    if ((threadIdx.x & 63) == 0) { sl[wv] = loss; sc[wv] = corr; }
    __syncthreads();
    if (threadIdx.x == 0) {
        partsum[blockIdx.x]       = sl[0] + sl[1] + sl[2] + sl[3];
        partsum[128 + blockIdx.x] = sc[0] + sc[1] + sc[2] + sc[3];
    }
}

// ---- k4: final scalar reduce ----------------------------------------------
__global__ void __launch_bounds__(128) final_kernel(const float* __restrict__ partsum,
                                                    float* __restrict__ out) {
    const int t = threadIdx.x;
    float l = partsum[t];
    float c = partsum[128 + t];
#pragma unroll
    for (int mask = 1; mask < 64; mask <<= 1) {
        l += __shfl_xor(l, mask);
        c += __shfl_xor(c, mask);
    }
    __shared__ float sl[2], sc[2];
    if ((t & 63) == 0) { sl[t >> 6] = l; sc[t >> 6] = c; }
    __syncthreads();
    if (t == 0) {
        out[0] = (sl[0] + sl[1]) * (1.f / (float)NROWS);
        out[1] = (sc[0] + sc[1]) * (1.f / (float)NROWS);
    }
}

extern "C" void kernel_launch(void* const* d_in, const int* in_sizes, int n_in,
                              void* d_out, int out_size, void* d_ws, size_t ws_size,
                              hipStream_t stream) {
    (void)in_sizes; (void)n_in; (void)out_size; (void)ws_size;
    const float* emb = (const float*)d_in[0];
    const float* lnw = (const float*)d_in[3];
    const float* lnb = (const float*)d_in[4];
    float* out = (float*)d_out;

    char* ws = (char*)d_ws;
    unsigned short* ebf = (unsigned short*)ws;                                   // 32 MB
    unsigned short* ck  = (unsigned short*)(ws + (size_t)NROWS * D_DIM * 2);     // 1 MB
    float* maxo_part = (float*)(ws + (size_t)NROWS * D_DIM * 2
                                   + (size_t)N_SPK * D_DIM * 2);                 // 512 KB
    float* own_part  = (float*)((char*)maxo_part + (size_t)NTILES * NROWS * 4);  // 128 KB
    float* partsum   = (float*)((char*)own_part + (size_t)NROWS * 4);            // 1 KB

    prep_kernel<<<N_SPK, 256, 0, stream>>>(emb, lnw, ebf, ck);
    gemm_kernel<<<GRID_G, 512, 0, stream>>>(ebf, ck, maxo_part, own_part);
    rowred_kernel<<<NROWS / 256, 256, 0, stream>>>(maxo_part, own_part, lnw, lnb, partsum);
    final_kernel<<<1, 128, 0, stream>>>(partsum, out);
}

// Round 11
// 56.881 us; speedup vs baseline: 5.1263x; 1.2442x over previous
//
#include <hip/hip_runtime.h>

// GE2E loss, N=1024 spk, M=32 utt, D=512.
// v11: fp8-e4m3 GEMM with real TLP. prep: emb fp32 -> e8 = fp8(8*emb) and
// ck8 = fp8(16*sgn(lw)*ck). gemm: 2048 blocks of 128x128 (4 waves, 36 KB LDS,
// ~115 VGPR, launch_bounds(256,3) -> 3-4 blocks/CU resident; independent
// blocks hide each other's stalls, m114/m97 mechanism). Simple dbuf loop:
// stage(t+1) -> ds_read_b64 frags -> 32 mfma_fp8 -> lgkm0/vmcnt0/barrier.
// LDS: 2 rows per 128B line, phys chunk = logical ^ (line&7) (0-conflict
// family), staged via global_load_lds w/ pre-swizzled source. sims scaled
// x128*sgn; /128 folded into rowred (monotone => max/argmax unaffected).

#define N_SPK 1024
#define M_UTT 32
#define D_DIM 512
#define NROWS (N_SPK * M_UTT)   // 32768
#define NTILES 8                // 1024/128 col tiles
#define MTILES 256              // 32768/128 row tiles
#define NWG (MTILES * NTILES)   // 2048
#define NKT 8                   // 512/64

typedef __attribute__((ext_vector_type(4))) float f32x4;

__device__ __forceinline__ void gload_lds16(const void* g, void* l) {
    __builtin_amdgcn_global_load_lds(
        (const __attribute__((address_space(1))) unsigned int*)g,
        (__attribute__((address_space(3))) unsigned int*)l, 16, 0, 0);
}

__device__ __forceinline__ float sigmoidf(float x) {
    return 1.f / (1.f + __expf(-x));
}

// ---- k1: e8 = fp8(8*emb), ck8 = fp8(16*sgn(lw)*mean_m emb) -----------------
__global__ void __launch_bounds__(256) prep_kernel(const float* __restrict__ emb,
                                                   const float* __restrict__ lnw,
                                                   unsigned int* __restrict__ e8,
                                                   unsigned int* __restrict__ ck8) {
    __shared__ float part[2][D_DIM];
    const int n = blockIdx.x;
    const int t = threadIdx.x;
    const int d4 = (t & 127) * 4;
    const int mh = t >> 7;
    const float* base = emb + (size_t)n * M_UTT * D_DIM;

    float4 acc = {0.f, 0.f, 0.f, 0.f};
#pragma unroll
    for (int mm = 0; mm < 16; ++mm) {
        const int m = mh * 16 + mm;
        const float4 v = *reinterpret_cast<const float4*>(base + m * D_DIM + d4);
        acc.x += v.x; acc.y += v.y; acc.z += v.z; acc.w += v.w;
        int w = __builtin_amdgcn_cvt_pk_fp8_f32(8.f * v.x, 8.f * v.y, 0, false);
        w = __builtin_amdgcn_cvt_pk_fp8_f32(8.f * v.z, 8.f * v.w, w, true);
        e8[(((size_t)(n * M_UTT + m)) * D_DIM + d4) >> 2] = (unsigned int)w;
    }
    *reinterpret_cast<float4*>(&part[mh][d4]) = acc;
    __syncthreads();
    if (t < 128) {
        const float sgn = (lnw[0] >= 0.f) ? 1.f : -1.f;
        const float sc = sgn * 0.5f;   // 16*sgn*(sum/32)
        const int d = t * 4;
        const float4 a = *reinterpret_cast<const float4*>(&part[0][d]);
        const float4 b = *reinterpret_cast<const float4*>(&part[1][d]);
        int w = __builtin_amdgcn_cvt_pk_fp8_f32((a.x + b.x) * sc, (a.y + b.y) * sc, 0, false);
        w = __builtin_amdgcn_cvt_pk_fp8_f32((a.z + b.z) * sc, (a.w + b.w) * sc, w, true);
        ck8[(((size_t)n) * D_DIM + d) >> 2] = (unsigned int)w;
    }
}

// ---- k2: fp8 GEMM, 128x128 blocks, 3-4 resident/CU -------------------------
__global__ void __launch_bounds__(256, 3)
gemm_kernel(const char* __restrict__ e8,
            const char* __restrict__ ck8,
            float* __restrict__ maxo_part,
            float* __restrict__ own_part) {
    // buf[c]: A 128x64 fp8 at [0,8192), B at [8192,16384).
    // line L (128 B) = rows {2L,2L+1}; logical chunk l = (row&1)*4 + kbyte/16,
    // stored at phys = l ^ (L&7).
    __shared__ __align__(16) char buf[2][16384];   // 32 KB
    __shared__ float redm[2][128];                 // 1 KB
    __shared__ float redo[2][128];                 // 1 KB

    const int tid  = threadIdx.x;
    const int lane = tid & 63;
    const int wv   = tid >> 6;
    const int lo   = lane & 15;
    const int hi   = lane >> 4;
    const int wm   = wv >> 1;   // 0..1 : 64-row half
    const int wn   = wv & 1;    // 0..1 : 64-col half

    // XCD map: xcd gets 32 consecutive mt x all 8 nt (A 2MB + ck 0.5MB in L2)
    const int raw   = blockIdx.x;
    const int xcd   = raw & 7;
    const int local = raw >> 3;              // 0..255
    const int mt    = xcd * 32 + (local >> 3);
    const int nt    = local & 7;
    const int r0    = mt * 128;
    const int n0    = nt * 128;

    // ---- staging map: per region 512 chunks (16B), 2 per thread ----
    const char* pA[2];
    const char* pB[2];
    int dA[2], dB[2];
#pragma unroll
    for (int j = 0; j < 2; ++j) {
        const int s   = j * 256 + tid;
        const int L   = s >> 3;
        const int l   = (s & 7) ^ (L & 7);
        const int row = 2 * L + (l >> 2);
        const int kch = l & 3;
        pA[j] = e8  + (size_t)(r0 + row) * D_DIM + kch * 16;
        pB[j] = ck8 + (size_t)(n0 + row) * D_DIM + kch * 16;
        dA[j] = s * 16;
        dB[j] = 8192 + s * 16;
    }

    auto stage = [&](int u) {
        char* bb = &buf[u & 1][0];
        const int ko = u * 64;   // 64 k-bytes per K-tile
#pragma unroll
        for (int j = 0; j < 2; ++j) {
            gload_lds16(pA[j] + ko, bb + dA[j]);
            gload_lds16(pB[j] + ko, bb + dB[j]);
        }
    };

    stage(0);
    asm volatile("s_waitcnt vmcnt(0)" ::: "memory");
    __builtin_amdgcn_s_barrier();

    // ---- frag read addressing (b64). row = wmBase + am*16 + lo ----
    // L&7 = (lo>>1)&7 (am,wm invariant); parity = lo&1.
    const int Lr    = lo >> 1;
    const int par   = lo & 1;
    const int phys0 = ((par << 2) | (hi >> 1))     ^ Lr;   // kk=0
    const int phys1 = ((par << 2) | 2 | (hi >> 1)) ^ Lr;   // kk=1
    const int a0 = (wm * 32 + Lr) * 128 + phys0 * 16 + (hi & 1) * 8;
    const int a1 = (wm * 32 + Lr) * 128 + phys1 * 16 + (hi & 1) * 8;
    const int b0 = 8192 + (wn * 32 + Lr) * 128 + phys0 * 16 + (hi & 1) * 8;
    const int b1 = 8192 + (wn * 32 + Lr) * 128 + phys1 * 16 + (hi & 1) * 8;

    f32x4 acc[4][4];
#pragma unroll
    for (int am = 0; am < 4; ++am)
#pragma unroll
        for (int an = 0; an < 4; ++an) acc[am][an] = (f32x4){0.f, 0.f, 0.f, 0.f};

    long a[4], b[4];

#pragma unroll
    for (int t = 0; t < NKT; ++t) {
        const char* bp = &buf[t & 1][0];
        if (t < NKT - 1) stage(t + 1);

        // kk = 0
#pragma unroll
        for (int am = 0; am < 4; ++am)
            a[am] = *reinterpret_cast<const long*>(bp + a0 + am * 1024);
#pragma unroll
        for (int an = 0; an < 4; ++an)
            b[an] = *reinterpret_cast<const long*>(bp + b0 + an * 1024);
        __builtin_amdgcn_s_setprio(1);
#pragma unroll
        for (int am = 0; am < 4; ++am)
#pragma unroll
            for (int an = 0; an < 4; ++an)
                acc[am][an] = __builtin_amdgcn_mfma_f32_16x16x32_fp8_fp8(
                    a[am], b[an], acc[am][an], 0, 0, 0);
        __builtin_amdgcn_s_setprio(0);

        // kk = 1
#pragma unroll
        for (int am = 0; am < 4; ++am)
            a[am] = *reinterpret_cast<const long*>(bp + a1 + am * 1024);
#pragma unroll
        for (int an = 0; an < 4; ++an)
            b[an] = *reinterpret_cast<const long*>(bp + b1 + an * 1024);
        __builtin_amdgcn_s_setprio(1);
#pragma unroll
        for (int am = 0; am < 4; ++am)
#pragma unroll
            for (int an = 0; an < 4; ++an)
                acc[am][an] = __builtin_amdgcn_mfma_f32_16x16x32_fp8_fp8(
                    a[am], b[an], acc[am][an], 0, 0, 0);
        __builtin_amdgcn_s_setprio(0);

        // end-of-tile: my ds_reads retired; my DMAs for t+1 landed; rendezvous
        asm volatile("s_waitcnt lgkmcnt(0)" ::: "memory");
        if (t < NKT - 1) asm volatile("s_waitcnt vmcnt(0)" ::: "memory");
        __builtin_amdgcn_s_barrier();
    }

    // ---- epilogue: per-row max (diag excluded, scaled x128*sgn) + own ----
    const float NEG = -1e30f;
#pragma unroll
    for (int am = 0; am < 4; ++am) {
#pragma unroll
        for (int reg = 0; reg < 4; ++reg) {
            const int rl   = wm * 64 + am * 16 + hi * 4 + reg;
            const int rowg = r0 + rl;
            const int spk  = rowg >> 5;
            float m = NEG, o = NEG;
#pragma unroll
            for (int an = 0; an < 4; ++an) {
                const int col = n0 + wn * 64 + an * 16 + lo;
                const float v = acc[am][an][reg];
                const bool dg = (col == spk);
                o = dg ? v : o;
                m = fmaxf(m, dg ? NEG : v);
            }
#pragma unroll
            for (int mask = 1; mask < 16; mask <<= 1) {
                m = fmaxf(m, __shfl_xor(m, mask));
                o = fmaxf(o, __shfl_xor(o, mask));
            }
            if (lo == 0) {
                redm[wn][rl] = m;
                redo[wn][rl] = o;
            }
        }
    }
    __syncthreads();

    if (tid < 128) {
        const float mo = fmaxf(redm[0][tid], redm[1][tid]);
        maxo_part[(size_t)nt * NROWS + r0 + tid] = mo;
        if (nt == (mt >> 5)) {   // this nt contains the block's own-speaker cols
            own_part[r0 + tid] = fmaxf(redo[0][tid], redo[1][tid]);
        }
    }
}

// ---- k3: per-row finish: combine 8 tile-maxes, sigmoid, loss/corr ----------
__global__ void __launch_bounds__(256) rowred_kernel(const float* __restrict__ maxo_part,
                                                     const float* __restrict__ own_part,
                                                     const float* __restrict__ lnw,
                                                     const float* __restrict__ lnb,
                                                     float* __restrict__ partsum) {
    const int r = blockIdx.x * 256 + threadIdx.x;
    const float lw = lnw[0], lb = lnb[0];
    const float sgn = (lw >= 0.f) ? 1.f : -1.f;
    const float alw = fabsf(lw);
    const float inv128 = 1.f / 128.f;

    float mo = maxo_part[r];
#pragma unroll
    for (int p = 1; p < NTILES; ++p)
        mo = fmaxf(mo, maxo_part[(size_t)p * NROWS + r]);
    const float O     = own_part[r];              // 128*sgn*(e.ck_own)
    const float t_own = sgn * O * inv128;
    const float ex    = (32.f * t_own - 1.f) * (1.f / 31.f);
    const float own_s = sigmoidf(lw * ex + lb);
    const float mo_s  = sigmoidf(alw * mo * inv128 + lb);
    float loss = 1.f - own_s + mo_s;
    float corr = (sgn * ex >= mo * inv128) ? 1.f : 0.f;

#pragma unroll
    for (int mask = 1; mask < 64; mask <<= 1) {
        loss += __shfl_xor(loss, mask);
        corr += __shfl_xor(corr, mask);
    }
    __shared__ float sl[4], sc[4];
    const int wv = threadIdx.x >> 6;
    if ((threadIdx.x & 63) == 0) { sl[wv] = loss; sc[wv] = corr; }
    __syncthreads();
    if (threadIdx.x == 0) {
        partsum[blockIdx.x]       = sl[0] + sl[1] + sl[2] + sl[3];
        partsum[128 + blockIdx.x] = sc[0] + sc[1] + sc[2] + sc[3];
    }
}

// ---- k4: final scalar reduce ----------------------------------------------
__global__ void __launch_bounds__(128) final_kernel(const float* __restrict__ partsum,
                                                    float* __restrict__ out) {
    const int t = threadIdx.x;
    float l = partsum[t];
    float c = partsum[128 + t];
#pragma unroll
    for (int mask = 1; mask < 64; mask <<= 1) {
        l += __shfl_xor(l, mask);
        c += __shfl_xor(c, mask);
    }
    __shared__ float sl[2], sc[2];
    if ((t & 63) == 0) { sl[t >> 6] = l; sc[t >> 6] = c; }
    __syncthreads();
    if (t == 0) {
        out[0] = (sl[0] + sl[1]) * (1.f / (float)NROWS);
        out[1] = (sc[0] + sc[1]) * (1.f / (float)NROWS);
    }
}

extern "C" void kernel_launch(void* const* d_in, const int* in_sizes, int n_in,
                              void* d_out, int out_size, void* d_ws, size_t ws_size,
                              hipStream_t stream) {
    (void)in_sizes; (void)n_in; (void)out_size; (void)ws_size;
    const float* emb = (const float*)d_in[0];
    const float* lnw = (const float*)d_in[3];
    const float* lnb = (const float*)d_in[4];
    float* out = (float*)d_out;

    char* ws = (char*)d_ws;
    char* e8  = ws;                                           // 16 MB
    char* ck8 = ws + (size_t)NROWS * D_DIM;                   // 512 KB
    float* maxo_part = (float*)(ck8 + (size_t)N_SPK * D_DIM); // 1 MB
    float* own_part  = (float*)((char*)maxo_part + (size_t)NTILES * NROWS * 4); // 128 KB
    float* partsum   = (float*)((char*)own_part + (size_t)NROWS * 4);           // 1 KB

    prep_kernel<<<N_SPK, 256, 0, stream>>>(emb, lnw, (unsigned int*)e8, (unsigned int*)ck8);
    gemm_kernel<<<NWG, 256, 0, stream>>>(e8, ck8, maxo_part, own_part);
    rowred_kernel<<<NROWS / 256, 256, 0, stream>>>(maxo_part, own_part, lnw, lnb, partsum);
    final_kernel<<<1, 128, 0, stream>>>(partsum, out);
}